// Round 18
// baseline (1146.908 us; speedup 1.0000x reference)
//
#include <hip/hip_runtime.h>

// ---------------- constants ----------------
#define M_TOK 18464      // 32*577 tokens
#define TSEQ  577
#define NBATCH 32
#define NH    16
#define HD    64
#define DIMM  1024
#define HIDD  4096
#define NTM2  73         // ceil(18464/256)

typedef __attribute__((ext_vector_type(4))) float f32x4;
typedef __attribute__((ext_vector_type(8))) short bf8;   // 8 bf16 (MFMA A/B frag)
typedef __attribute__((ext_vector_type(8))) short s8v;
typedef __attribute__((ext_vector_type(4))) short s4v;

__device__ __forceinline__ short f2bf(float f) {
  union { float f; unsigned u; } c; c.f = f;
  unsigned u = c.u;
  unsigned r = (u + 0x7fffu + ((u >> 16) & 1u)) >> 16;  // RNE
  return (short)r;
}

// async global->LDS, 16B per lane; dest = wave-uniform base + lane*16
__device__ __forceinline__ void gld_lds16(const short* g, short* l) {
  __builtin_amdgcn_global_load_lds(
      (const __attribute__((address_space(1))) unsigned int*)g,
      (__attribute__((address_space(3))) unsigned int*)l, 16, 0, 0);
}

#define MFMA16(a, b, c) __builtin_amdgcn_mfma_f32_16x16x32_bf16(a, b, c, 0, 0, 0)

// ---------------- weight convert + transpose: W[K][N] f32 -> WT[N][K] bf16 ----------------
__global__ __launch_bounds__(256) void conv_t_kernel(const float* __restrict__ W,
                                                     short* __restrict__ WT,
                                                     int K, int N) {
  __shared__ short tile[32][33];
  int bx = blockIdx.x;  // n tile
  int by = blockIdx.y;  // k tile
  int t = threadIdx.x;
  int c = t & 31, r = t >> 5;  // 32 cols x 8 rows
#pragma unroll
  for (int rr = r; rr < 32; rr += 8)
    tile[rr][c] = f2bf(W[(size_t)(by * 32 + rr) * N + bx * 32 + c]);
  __syncthreads();
#pragma unroll
  for (int rr = r; rr < 32; rr += 8)
    WT[(size_t)(bx * 32 + rr) * K + by * 32 + c] = tile[c][rr];
}

// ---------------- layernorm: wave-per-row, f32 [M][1024] -> bf16 [M][1024] ----------------
__global__ __launch_bounds__(256) void ln_kernel(const float* __restrict__ x,
                                                 const float* __restrict__ g,
                                                 const float* __restrict__ b,
                                                 short* __restrict__ out) {
  int w = threadIdx.x >> 6, l = threadIdx.x & 63;
  int row = blockIdx.x * 4 + w;   // grid 4616 * 4 = 18464 exactly
  const float4* xr = (const float4*)(x + (size_t)row * DIMM);
  const float4* g4 = (const float4*)g;
  const float4* b4 = (const float4*)b;
  float4 v[4];
  float s1 = 0.f;
#pragma unroll
  for (int i = 0; i < 4; ++i) {
    v[i] = xr[i * 64 + l];
    s1 += v[i].x + v[i].y + v[i].z + v[i].w;
  }
#pragma unroll
  for (int m = 1; m < 64; m <<= 1) s1 += __shfl_xor(s1, m);
  float mu = s1 * (1.0f / 1024.0f);
  float s2 = 0.f;
#pragma unroll
  for (int i = 0; i < 4; ++i) {
    float dx = v[i].x - mu, dy = v[i].y - mu, dz = v[i].z - mu, dw = v[i].w - mu;
    s2 += dx * dx + dy * dy + dz * dz + dw * dw;
  }
#pragma unroll
  for (int m = 1; m < 64; m <<= 1) s2 += __shfl_xor(s2, m);
  float rs = rsqrtf(s2 * (1.0f / 1024.0f) + 1e-6f);
#pragma unroll
  for (int i = 0; i < 4; ++i) {
    float4 gv = g4[i * 64 + l], bv = b4[i * 64 + l];
    s4v o;
    o[0] = f2bf((v[i].x - mu) * rs * gv.x + bv.x);
    o[1] = f2bf((v[i].y - mu) * rs * gv.y + bv.y);
    o[2] = f2bf((v[i].z - mu) * rs * gv.z + bv.z);
    o[3] = f2bf((v[i].w - mu) * rs * gv.w + bv.w);
    *(s4v*)(out + (size_t)row * DIMM + (i * 64 + l) * 4) = o;
  }
}

// ---------------- GEMM 256x256x64, 8-phase counted-vmcnt pipeline ----------------
// C[M][N] = A[M][K](bf16, lda) @ BT[N][K](bf16, ldb)^T + bias
// EPI 0: bf16 = C+bias | EPI 1: f32 = C+bias+res | EPI 2: bf16 = gelu(C+bias) | EPI 3: f32 += C
// 512 thr, 8 waves 2M x 4N, per-wave 128x64 out = acc[8][4] (2x FLOP per LDS byte vs 64x64).
// B-frags register-resident across the 4 phases of a K-tile => B-LDS dead after phase 1;
// A quadrants die per phase (full A dead after phase 4). Even/odd K-tiles use FIXED bufs
// (t and t+2 share parity). Stage schedule (every target provably dead at issue):
//   hk=0: P1: A(t1)l  P2: A(t1)h  P3: B(t0+2)l  P4: B(t0+2)h   (into odd-A / even-B)
//   hk=1: P5: A(t0+2)l P6: A(t0+2)h P7: B(t1+2)l P8: B(t1+2)h  (into even-A / odd-B)
// Gates: vmcnt(4) at end-P4 (protects P5's B(t1)+A(t1) reads) and end-P8 (protects next
// iter's B(t0+2)+A(t0+2)); vmcnt(0) on last iter. Prologue: B0,A0,B1 (6 half-tiles)+vmcnt(4).
template <int EPI>
__global__ __launch_bounds__(512, 1) void gemm256_kernel(const short* __restrict__ A,
                                                         const short* __restrict__ BT,
                                                         const float* __restrict__ bias,
                                                         const float* res, short* outh,
                                                         float* outf, int M, int K, int N,
                                                         int lda, int ldb, int ntm, int ntn) {
  __shared__ short lds[65536];  // 128 KB: A-even 0 | B-even 16384 | A-odd 32768 | B-odd 49152
  // bijective 4x2 XCD region map (R17-proven)
  int grid = ntm * ntn;
  int qd = grid >> 3, rd = grid & 7;
  int x = blockIdx.x & 7, il = blockIdx.x >> 3;
  int gid = x * qd + (x < rd ? x : rd) + il;
  int tnh = ntn >> 1;
  int qa = ntm >> 2, ra = ntm & 3;
  int tm = 0, tn = 0, rem = gid;
#pragma unroll
  for (int rg = 0; rg < 8; ++rg) {
    int i = rg >> 1, j = rg & 1;
    int rows = qa + (i < ra ? 1 : 0);
    int cnt = rows * tnh;
    if (rem < cnt) {
      int rowstart = i * qa + (i < ra ? i : ra);
      tm = rowstart + rem / tnh;
      tn = j * tnh + rem % tnh;
      rem = 0x7fffffff;
    } else if (rem != 0x7fffffff) {
      rem -= cnt;
    }
  }
  int m0 = tm * 256, n0 = tn * 256;
  int t = threadIdx.x, l = t & 63;
  int w = t >> 6, wm = w >> 2, wn = w & 3;  // 2M x 4N
  f32x4 acc[8][4] = {};
  const int NKT = K >> 6;
  const int NIT = NKT >> 1;

  // stage one 128x64 half-tile (2 x gld_lds16/thread), chunk^(row&7) swizzled source
  auto STAGE = [&](const short* G, int rbase, int rmax, int ld, int kt, int half, int base) {
    int kcol = kt << 6;
#pragma unroll
    for (int j = 0; j < 2; ++j) {
      int c = j * 512 + t;
      int row = c >> 3, cs = (c & 7) ^ (row & 7);
      int gr = rbase + half * 128 + row;
      if (gr > rmax) gr = rmax;
      gld_lds16(G + (size_t)gr * ld + kcol + cs * 8,
                &lds[base + half * 8192 + (j * 512 + (t & 448)) * 8]);
    }
  };

  // prologue: B0l,B0h,A0l,A0h,B1l,B1h (12 loads); need B0+A0 -> vmcnt(4)
  STAGE(BT, n0, N - 1, ldb, 0, 0, 16384);
  STAGE(BT, n0, N - 1, ldb, 0, 1, 16384);
  STAGE(A, m0, M - 1, lda, 0, 0, 0);
  STAGE(A, m0, M - 1, lda, 0, 1, 0);
  STAGE(BT, n0, N - 1, ldb, 1, 0, 49152);
  STAGE(BT, n0, N - 1, ldb, 1, 1, 49152);
  asm volatile("s_waitcnt vmcnt(4)" ::: "memory");
  __builtin_amdgcn_s_barrier();
  __builtin_amdgcn_sched_barrier(0);

  for (int it = 0; it < NIT; ++it) {
    int t0 = 2 * it, t1 = 2 * it + 1;
    bool more = (it < NIT - 1);
#pragma unroll
    for (int hk = 0; hk < 2; ++hk) {
      int aB = hk ? 32768 : 0, bB = hk ? 49152 : 16384;
      bf8 bfr[4][2], af[2][2];
#pragma unroll
      for (int q = 0; q < 4; ++q) {
        if (q == 0) {
#pragma unroll
          for (int nf = 0; nf < 4; ++nf)
#pragma unroll
            for (int ks = 0; ks < 2; ++ks) {
              int rB = wn * 64 + nf * 16 + (l & 15);
              int g = ks * 4 + (l >> 4);
              bfr[nf][ks] = *(const bf8*)&lds[bB + (rB >> 7) * 8192 + (rB & 127) * 64 +
                                              ((g ^ (rB & 7)) * 8)];
            }
        }
#pragma unroll
        for (int i2 = 0; i2 < 2; ++i2)
#pragma unroll
          for (int ks = 0; ks < 2; ++ks) {
            int r = wm * 128 + q * 32 + i2 * 16 + (l & 15);
            int g = ks * 4 + (l >> 4);
            af[i2][ks] = *(const bf8*)&lds[aB + (r >> 7) * 8192 + (r & 127) * 64 +
                                           ((g ^ (r & 7)) * 8)];
          }
        // stage schedule (targets dead; see header)
        if (hk == 0) {
          if (q == 0)      STAGE(A, m0, M - 1, lda, t1, 0, 32768);
          else if (q == 1) STAGE(A, m0, M - 1, lda, t1, 1, 32768);
          else if (q == 2) { if (more) STAGE(BT, n0, N - 1, ldb, t0 + 2, 0, 16384); }
          else             { if (more) STAGE(BT, n0, N - 1, ldb, t0 + 2, 1, 16384); }
        } else {
          if (q == 0)      { if (more) STAGE(A, m0, M - 1, lda, t0 + 2, 0, 0); }
          else if (q == 1) { if (more) STAGE(A, m0, M - 1, lda, t0 + 2, 1, 0); }
          else if (q == 2) { if (more) STAGE(BT, n0, N - 1, ldb, t1 + 2, 0, 49152); }
          else             { if (more) STAGE(BT, n0, N - 1, ldb, t1 + 2, 1, 49152); }
        }
        __builtin_amdgcn_s_barrier();
        asm volatile("s_waitcnt lgkmcnt(0)" ::: "memory");
        __builtin_amdgcn_sched_barrier(0);
        __builtin_amdgcn_s_setprio(1);
#pragma unroll
        for (int i2 = 0; i2 < 2; ++i2)
#pragma unroll
          for (int nf = 0; nf < 4; ++nf)
#pragma unroll
            for (int ks = 0; ks < 2; ++ks)
              acc[q * 2 + i2][nf] = MFMA16(af[i2][ks], bfr[nf][ks], acc[q * 2 + i2][nf]);
        __builtin_amdgcn_s_setprio(0);
        if (q == 3) {  // gate before next half-iteration's ds_reads
          if (more) asm volatile("s_waitcnt vmcnt(4)" ::: "memory");
          else      asm volatile("s_waitcnt vmcnt(0)" ::: "memory");
        }
        __builtin_amdgcn_s_barrier();
        __builtin_amdgcn_sched_barrier(0);
      }
    }
  }

  // epilogue: C/D layout col=lane&15, row=4*(lane>>4)+reg; per-wave 128x64 at
  // (wm*128, wn*64). EPI0/2: LDS-staged 64-row groups -> full-line 16B stores.
  if constexpr (EPI == 0 || EPI == 2) {
#pragma unroll
    for (int rg = 0; rg < 4; ++rg) {
      if (wm == (rg >> 1)) {
        int i0 = (rg & 1) * 4;
#pragma unroll
        for (int jf = 0; jf < 4; ++jf) {
          int lcol = wn * 64 + jf * 16 + (l & 15);
          float bz = bias[n0 + lcol];
#pragma unroll
          for (int ii = 0; ii < 4; ++ii) {
#pragma unroll
            for (int qv = 0; qv < 4; ++qv) {
              int lrow = ii * 16 + (l >> 4) * 4 + qv;
              float v = acc[i0 + ii][jf][qv] + bz;
              if constexpr (EPI == 2) v = 0.5f * v * (1.0f + erff(v * 0.70710678118f));
              lds[lrow * 264 + lcol] = f2bf(v);
            }
          }
        }
      }
      __syncthreads();
#pragma unroll
      for (int it2 = 0; it2 < 4; ++it2) {
        int c = it2 * 512 + t;
        int lrow = c >> 5, ch = c & 31;
        int grow = m0 + rg * 64 + lrow;
        s4v lo = *(const s4v*)&lds[lrow * 264 + ch * 8];
        s4v hi = *(const s4v*)&lds[lrow * 264 + ch * 8 + 4];
        s8v vv = __builtin_shufflevector(lo, hi, 0, 1, 2, 3, 4, 5, 6, 7);
        if (grow < M)
          __builtin_nontemporal_store(vv, (s8v*)(outh + (size_t)grow * N + n0 + ch * 8));
      }
      __syncthreads();
    }
  } else {
#pragma unroll
    for (int jf = 0; jf < 4; ++jf) {
      int col = n0 + wn * 64 + jf * 16 + (l & 15);
      float bz = (EPI == 3) ? 0.f : bias[col];
#pragma unroll
      for (int ifr = 0; ifr < 8; ++ifr) {
        int rbase = m0 + wm * 128 + ifr * 16 + (l >> 4) * 4;
#pragma unroll
        for (int qv = 0; qv < 4; ++qv) {
          int row = rbase + qv;
          if (row < M) {
            float v = acc[ifr][jf][qv] + bz;
            size_t idx = (size_t)row * N + col;
            if constexpr (EPI == 1) {
              outf[idx] = v + res[idx];
            } else {
              outf[idx] += v;
            }
          }
        }
      }
    }
  }
}

// ---------------- flash attention: swapped QK^T, in-lane P pack, no-max softmax ------
// (R16/R17-proven: absmax 0.03125.)
__global__ __launch_bounds__(256, 4) void attn_kernel(const short* __restrict__ qkv,
                                                      short* __restrict__ aout) {
  __shared__ short lK[64 * 64];
  __shared__ short lV[64 * 64];
  __shared__ short lP[4 * 16 * 64];   // per-wave 16-row P, reused per row-group
  int bid = blockIdx.x;
  int i5 = bid >> 3;
  int bh = ((bid & 7) << 6) + i5 / 5;
  int qt = i5 - (i5 / 5) * 5;          // 0..4, 128 q-rows each
  int b = bh >> 4, h = bh & 15;
  int t = threadIdx.x, w = t >> 6, l = t & 63;
  int m0 = qt * 128;
  const size_t tokbase = (size_t)b * TSEQ;
  unsigned lvb = (unsigned)(uintptr_t)&lV[0];
  const bf8 vones = {0x3F80, 0x3F80, 0x3F80, 0x3F80, 0x3F80, 0x3F80, 0x3F80, 0x3F80};

  bf8 qf[2][2];
#pragma unroll
  for (int g = 0; g < 2; ++g) {
    int tq0 = m0 + w * 32 + g * 16 + (l & 15);
    if (tq0 > TSEQ - 1) tq0 = TSEQ - 1;
    const short* qrow = qkv + (tokbase + tq0) * 3072 + h * 64;
    qf[g][0] = *(const bf8*)(qrow + (l >> 4) * 8);
    qf[g][1] = *(const bf8*)(qrow + 32 + (l >> 4) * 8);
  }

  f32x4 o_acc[2][4] = {};
  f32x4 l_acc[2] = {};

  for (int kt = 0; kt < 10; ++kt) {
    __syncthreads();
#pragma unroll
    for (int i = 0; i < 2; i++) {
      int L = i * 256 + t;
      int key = L >> 3;
      int cd = (L & 7) ^ (key & 7);
      int tok = kt * 64 + key; if (tok > TSEQ - 1) tok = TSEQ - 1;
      gld_lds16(qkv + (tokbase + tok) * 3072 + 1024 + h * 64 + cd * 8,
                &lK[(i * 256 + w * 64) * 8]);
    }
#pragma unroll
    for (int i = 0; i < 2; i++) {
      int L = i * 256 + t;
      int k = (L >> 5) * 4 + ((L >> 1) & 3);
      int c = ((L >> 3) & 3) * 2 + (L & 1);
      int tok = kt * 64 + k; if (tok > TSEQ - 1) tok = TSEQ - 1;
      gld_lds16(qkv + (tokbase + tok) * 3072 + 2048 + h * 64 + c * 8,
                &lV[(i * 256 + w * 64) * 8]);
    }
    __syncthreads();

#pragma unroll
    for (int g = 0; g < 2; ++g) {
      __builtin_amdgcn_s_setprio(1);
#pragma unroll
      for (int nf = 0; nf < 4; ++nf) {
        f32x4 a = {};
#pragma unroll
        for (int ks = 0; ks < 2; ++ks) {
          int keyrow = nf * 16 + (l & 15);
          int cp = (ks * 4 + (l >> 4)) ^ (keyrow & 7);
          bf8 kf = *(const bf8*)&lK[keyrow * 64 + cp * 8];
          a = MFMA16(kf, qf[g][ks], a);
        }
        float s0 = a[0] * 0.18033688011f, s1 = a[1] * 0.18033688011f;
        float s2 = a[2] * 0.18033688011f, s3 = a[3] * 0.18033688011f;
        if (kt == 9) {
          int kb = 576 + nf * 16 + 4 * (l >> 4);
          if (kb + 0 >= TSEQ) s0 = -1e30f;
          if (kb + 1 >= TSEQ) s1 = -1e30f;
          if (kb + 2 >= TSEQ) s2 = -1e30f;
          if (kb + 3 >= TSEQ) s3 = -1e30f;
        }
        float e0, e1, e2, e3;
        asm("v_exp_f32 %0, %1" : "=v"(e0) : "v"(s0));
        asm("v_exp_f32 %0, %1" : "=v"(e1) : "v"(s1));
        asm("v_exp_f32 %0, %1" : "=v"(e2) : "v"(s2));
        asm("v_exp_f32 %0, %1" : "=v"(e3) : "v"(s3));
        unsigned d0, d1;
        asm("v_cvt_pk_bf16_f32 %0, %1, %2" : "=v"(d0) : "v"(e0), "v"(e1));
        asm("v_cvt_pk_bf16_f32 %0, %1, %2" : "=v"(d1) : "v"(e2), "v"(e3));
        int row = l & 15;
        int chunk = 2 * nf + ((l >> 4) >> 1);
        int cs = chunk ^ (row & 7);
        int base = w * 1024 + row * 64 + cs * 8 + 4 * ((l >> 4) & 1);
        *(unsigned*)&lP[base] = d0;
        *(unsigned*)&lP[base + 2] = d1;
      }
      __builtin_amdgcn_s_setprio(0);
      asm volatile("s_waitcnt lgkmcnt(0)" ::: "memory");
      __builtin_amdgcn_sched_barrier(0);

#pragma unroll
      for (int ks = 0; ks < 2; ++ks) {
        int qr = l & 15;
        int cp = (ks * 4 + (l >> 4)) ^ (qr & 7);
        bf8 pf = *(const bf8*)&lP[w * 1024 + qr * 64 + cp * 8];
        unsigned kq0 = (unsigned)(ks * 8 + (l >> 4) * 2);
        unsigned abase = lvb + kq0 * 512u + (unsigned)(l & 15) * 8u;
        s4v ra0, ra1, rb0, rb1, rc0, rc1, rd0, rd1;
        asm volatile("ds_read_b64_tr_b16 %0, %1" : "=v"(ra0) : "v"(abase));
        asm volatile("ds_read_b64_tr_b16 %0, %1" : "=v"(ra1) : "v"(abase + 512u));
        asm volatile("ds_read_b64_tr_b16 %0, %1" : "=v"(rb0) : "v"(abase + 128u));
        asm volatile("ds_read_b64_tr_b16 %0, %1" : "=v"(rb1) : "v"(abase + 640u));
        asm volatile("ds_read_b64_tr_b16 %0, %1" : "=v"(rc0) : "v"(abase + 256u));
        asm volatile("ds_read_b64_tr_b16 %0, %1" : "=v"(rc1) : "v"(abase + 768u));
        asm volatile("ds_read_b64_tr_b16 %0, %1" : "=v"(rd0) : "v"(abase + 384u));
        asm volatile("ds_read_b64_tr_b16 %0, %1" : "=v"(rd1) : "v"(abase + 896u));
        asm volatile("s_waitcnt lgkmcnt(0)" ::: "memory");
        __builtin_amdgcn_sched_barrier(0);
        bf8 vfa = __builtin_shufflevector(ra0, ra1, 0, 1, 2, 3, 4, 5, 6, 7);
        bf8 vfb = __builtin_shufflevector(rb0, rb1, 0, 1, 2, 3, 4, 5, 6, 7);
        bf8 vfc = __builtin_shufflevector(rc0, rc1, 0, 1, 2, 3, 4, 5, 6, 7);
        bf8 vfd = __builtin_shufflevector(rd0, rd1, 0, 1, 2, 3, 4, 5, 6, 7);
        __builtin_amdgcn_s_setprio(1);
        l_acc[g] = MFMA16(pf, vones, l_acc[g]);
        o_acc[g][0] = MFMA16(pf, vfa, o_acc[g][0]);
        o_acc[g][1] = MFMA16(pf, vfb, o_acc[g][1]);
        o_acc[g][2] = MFMA16(pf, vfc, o_acc[g][2]);
        o_acc[g][3] = MFMA16(pf, vfd, o_acc[g][3]);
        __builtin_amdgcn_s_setprio(0);
      }
    }
  }
#pragma unroll
  for (int g = 0; g < 2; ++g)
#pragma unroll
    for (int df = 0; df < 4; df++)
#pragma unroll
      for (int q = 0; q < 4; q++) {
        int tq = m0 + w * 32 + g * 16 + (l >> 4) * 4 + q;
        if (tq < TSEQ) {
          float val = o_acc[g][df][q] / l_acc[g][q];
          aout[(tokbase + tq) * DIMM + h * 64 + df * 16 + (l & 15)] = f2bf(val);
        }
      }
}

// ---------------- launch ----------------
extern "C" void kernel_launch(void* const* d_in, const int* in_sizes, int n_in,
                              void* d_out, int out_size, void* d_ws, size_t ws_size,
                              hipStream_t stream) {
  const float* x      = (const float*)d_in[0];
  const float* ln1_g  = (const float*)d_in[1];
  const float* ln1_b  = (const float*)d_in[2];
  const float* qkv_w  = (const float*)d_in[3];
  const float* qkv_b  = (const float*)d_in[4];
  const float* proj_w = (const float*)d_in[5];
  const float* proj_b = (const float*)d_in[6];
  const float* ln2_g  = (const float*)d_in[7];
  const float* ln2_b  = (const float*)d_in[8];
  const float* fc1_w  = (const float*)d_in[9];
  const float* fc1_b  = (const float*)d_in[10];
  const float* fc2_w  = (const float*)d_in[11];
  const float* fc2_b  = (const float*)d_in[12];
  float* out = (float*)d_out;

  const size_t REQ = (size_t)(12582912 + (size_t)M_TOK * 1024 + (size_t)M_TOK * 3072) * 2;
  if (ws_size < REQ) return;

  short* w_qkv  = (short*)d_ws;                      // [3072][1024]
  short* w_proj = w_qkv + (size_t)3072 * 1024;       // [1024][1024]
  short* w_fc1  = w_proj + (size_t)1024 * 1024;      // [4096][1024]
  short* w_fc2  = w_fc1 + (size_t)4096 * 1024;       // [1024][4096]
  short* bufA   = w_fc2 + (size_t)1024 * 4096;       // [M][1024]
  short* bufB   = bufA + (size_t)M_TOK * 1024;       // [M][3072] / FFN h-chunks [M][2048]

  dim3 blk(256);
  dim3 blk512(512);
  conv_t_kernel<<<dim3(3072 / 32, 1024 / 32), blk, 0, stream>>>(qkv_w, w_qkv, 1024, 3072);
  conv_t_kernel<<<dim3(1024 / 32, 1024 / 32), blk, 0, stream>>>(proj_w, w_proj, 1024, 1024);
  conv_t_kernel<<<dim3(4096 / 32, 1024 / 32), blk, 0, stream>>>(fc1_w, w_fc1, 1024, 4096);
  conv_t_kernel<<<dim3(1024 / 32, 4096 / 32), blk, 0, stream>>>(fc2_w, w_fc2, 4096, 1024);
  // LN1: x -> bufA
  ln_kernel<<<M_TOK / 4, blk, 0, stream>>>(x, ln1_g, ln1_b, bufA);
  // QKV: bufA @ w_qkv^T -> bufB   (grid 73*12 = 876)
  gemm256_kernel<0><<<NTM2 * 12, blk512, 0, stream>>>(bufA, w_qkv, qkv_b, nullptr, bufB,
                                                      nullptr, M_TOK, 1024, 3072, 1024, 1024,
                                                      NTM2, 12);
  // attention: bufB -> bufA   (flat 2560, XCD-clustered 5 q-tiles per (b,h))
  attn_kernel<<<2560, blk, 0, stream>>>(bufB, bufA);
  // proj + residual(x) -> out (x1)   (grid 292)
  gemm256_kernel<1><<<NTM2 * 4, blk512, 0, stream>>>(bufA, w_proj, proj_b, x, nullptr, out,
                                                     M_TOK, 1024, 1024, 1024, 1024, NTM2, 4);
  // LN2 on x1 -> bufA
  ln_kernel<<<M_TOK / 4, blk, 0, stream>>>(out, ln2_g, ln2_b, bufA);
  // FFN in 2 hidden-dim chunks of 2048 (h chunk lives in bufB)
  for (int c = 0; c < 2; ++c) {
    // FC1 chunk + GELU: bufA @ w_fc1[c*2048:+2048]^T -> bufB [M][2048]  (grid 584)
    gemm256_kernel<2><<<NTM2 * 8, blk512, 0, stream>>>(bufA, w_fc1 + (size_t)c * 2048 * 1024,
                                                       fc1_b + c * 2048, nullptr, bufB, nullptr,
                                                       M_TOK, 1024, 2048, 1024, 1024, NTM2, 8);
    // FC2 chunk: out (+)= bufB @ w_fc2[:, c*2048:+2048]^T  (grid 292)
    if (c == 0) {
      gemm256_kernel<1><<<NTM2 * 4, blk512, 0, stream>>>(bufB, w_fc2 + (size_t)c * 2048, fc2_b,
                                                         out, nullptr, out, M_TOK, 2048, 1024,
                                                         2048, 4096, NTM2, 4);
    } else {
      gemm256_kernel<3><<<NTM2 * 4, blk512, 0, stream>>>(bufB, w_fc2 + (size_t)c * 2048, fc2_b,
                                                         out, nullptr, out, M_TOK, 2048, 1024,
                                                         2048, 4096, NTM2, 4);
    }
  }
}

// Round 19
// 926.492 us; speedup vs baseline: 1.2379x; 1.2379x over previous
//
#include <hip/hip_runtime.h>

// ---------------- constants ----------------
#define M_TOK 18464      // 32*577 tokens
#define TSEQ  577
#define NBATCH 32
#define NH    16
#define HD    64
#define DIMM  1024
#define HIDD  4096
#define NTMK  145        // ceil(18464/128)

typedef __attribute__((ext_vector_type(4))) float f32x4;
typedef __attribute__((ext_vector_type(8))) short bf8;   // 8 bf16 (MFMA A/B frag)
typedef __attribute__((ext_vector_type(8))) short s8v;
typedef __attribute__((ext_vector_type(4))) short s4v;

__device__ __forceinline__ short f2bf(float f) {
  union { float f; unsigned u; } c; c.f = f;
  unsigned u = c.u;
  unsigned r = (u + 0x7fffu + ((u >> 16) & 1u)) >> 16;  // RNE
  return (short)r;
}

// async global->LDS, 16B per lane; dest = wave-uniform base + lane*16
__device__ __forceinline__ void gld_lds16(const short* g, short* l) {
  __builtin_amdgcn_global_load_lds(
      (const __attribute__((address_space(1))) unsigned int*)g,
      (__attribute__((address_space(3))) unsigned int*)l, 16, 0, 0);
}

#define MFMA16(a, b, c) __builtin_amdgcn_mfma_f32_16x16x32_bf16(a, b, c, 0, 0, 0)

// ---------------- weight convert + transpose: W[K][N] f32 -> WT[N][K] bf16 ----------------
__global__ __launch_bounds__(256) void conv_t_kernel(const float* __restrict__ W,
                                                     short* __restrict__ WT,
                                                     int K, int N) {
  __shared__ short tile[32][33];
  int bx = blockIdx.x;  // n tile
  int by = blockIdx.y;  // k tile
  int t = threadIdx.x;
  int c = t & 31, r = t >> 5;  // 32 cols x 8 rows
#pragma unroll
  for (int rr = r; rr < 32; rr += 8)
    tile[rr][c] = f2bf(W[(size_t)(by * 32 + rr) * N + bx * 32 + c]);
  __syncthreads();
#pragma unroll
  for (int rr = r; rr < 32; rr += 8)
    WT[(size_t)(bx * 32 + rr) * K + by * 32 + c] = tile[c][rr];
}

// ---------------- layernorm: wave-per-row, f32 [M][1024] -> bf16 [M][1024] ----------------
__global__ __launch_bounds__(256) void ln_kernel(const float* __restrict__ x,
                                                 const float* __restrict__ g,
                                                 const float* __restrict__ b,
                                                 short* __restrict__ out) {
  int w = threadIdx.x >> 6, l = threadIdx.x & 63;
  int row = blockIdx.x * 4 + w;   // grid 4616 * 4 = 18464 exactly
  const float4* xr = (const float4*)(x + (size_t)row * DIMM);
  const float4* g4 = (const float4*)g;
  const float4* b4 = (const float4*)b;
  float4 v[4];
  float s1 = 0.f;
#pragma unroll
  for (int i = 0; i < 4; ++i) {
    v[i] = xr[i * 64 + l];
    s1 += v[i].x + v[i].y + v[i].z + v[i].w;
  }
#pragma unroll
  for (int m = 1; m < 64; m <<= 1) s1 += __shfl_xor(s1, m);
  float mu = s1 * (1.0f / 1024.0f);
  float s2 = 0.f;
#pragma unroll
  for (int i = 0; i < 4; ++i) {
    float dx = v[i].x - mu, dy = v[i].y - mu, dz = v[i].z - mu, dw = v[i].w - mu;
    s2 += dx * dx + dy * dy + dz * dz + dw * dw;
  }
#pragma unroll
  for (int m = 1; m < 64; m <<= 1) s2 += __shfl_xor(s2, m);
  float rs = rsqrtf(s2 * (1.0f / 1024.0f) + 1e-6f);
#pragma unroll
  for (int i = 0; i < 4; ++i) {
    float4 gv = g4[i * 64 + l], bv = b4[i * 64 + l];
    s4v o;
    o[0] = f2bf((v[i].x - mu) * rs * gv.x + bv.x);
    o[1] = f2bf((v[i].y - mu) * rs * gv.y + bv.y);
    o[2] = f2bf((v[i].z - mu) * rs * gv.z + bv.z);
    o[3] = f2bf((v[i].w - mu) * rs * gv.w + bv.w);
    *(s4v*)(out + (size_t)row * DIMM + (i * 64 + l) * 4) = o;
  }
}

// ---------------- GEMM 128x128x64, single-buffer, 4 blocks/CU, 4x2 XCD region map ------
// C[M][N] = A[M][K](bf16, lda) @ BT[N][K](bf16, ldb)^T + bias
// EPI 0: bf16 = C+bias | EPI 1: f32 = C+bias+res | EPI 2: bf16 = gelu(C+bias) | EPI 3: f32 += C
// R13/R17-proven best structure. R18 lesson: 256^2 8-phase counted-vmcnt lands at
// MfmaUtil 15% (4th failed deep-schedule attempt); this TLP-first form wins at 21%.
// R14 lesson: bounds (256,5) spills the accumulator. Keep 4.
template <int EPI>
__global__ __launch_bounds__(256, 4) void gemm_kernel(const short* __restrict__ A,
                                                      const short* __restrict__ BT,
                                                      const float* __restrict__ bias,
                                                      const float* res, short* outh,
                                                      float* outf, int M, int K, int N,
                                                      int lda, int ldb, int ntm, int ntn) {
  __shared__ short lds[16384];   // 32 KB: lA | lB during K-loop, C-staging in epilogue
  short* lA = lds;
  short* lB = lds + 8192;
  // bijective gid: contiguous slice of region-major tile list per XCD
  int grid = ntm * ntn;
  int qd = grid >> 3, rd = grid & 7;
  int x = blockIdx.x & 7, il = blockIdx.x >> 3;
  int gid = x * qd + (x < rd ? x : rd) + il;
  // regions: 4 tm-groups x 2 tn-halves, region-major (i*2+j), tn-inner within region
  int tnh = ntn >> 1;
  int qa = ntm >> 2, ra = ntm & 3;
  int tm = 0, tn = 0, rem = gid;
#pragma unroll
  for (int rg = 0; rg < 8; ++rg) {
    int i = rg >> 1, j = rg & 1;
    int rows = qa + (i < ra ? 1 : 0);
    int cnt = rows * tnh;
    if (rem < cnt) {
      int rowstart = i * qa + (i < ra ? i : ra);
      tm = rowstart + rem / tnh;
      tn = j * tnh + rem % tnh;
      rem = 0x7fffffff;  // found; skip remaining regions
    } else if (rem != 0x7fffffff) {
      rem -= cnt;
    }
  }
  int m0 = tm * 128, n0 = tn * 128;
  int t = threadIdx.x, l = t & 63;
  int w = t >> 6, wm = w >> 1, wn = w & 1;
  f32x4 acc[4][4] = {};
  const int NKT = K >> 6;

  for (int it = 0; it < NKT; ++it) {
    __syncthreads();  // previous tile's readers done
    int kcol = it << 6;
#pragma unroll
    for (int i = 0; i < 4; i++) {
      int L = i * 256 + t;
      int row = L >> 3, cs = (L & 7) ^ (row & 7);
      int mg = m0 + row;
      if (mg > M - 1) mg = M - 1;
      gld_lds16(A + (size_t)mg * lda + kcol + cs * 8,
                &lA[(i * 256 + (t & 448)) * 8]);
    }
#pragma unroll
    for (int i = 0; i < 4; i++) {
      int L = i * 256 + t;
      int row = L >> 3, cs = (L & 7) ^ (row & 7);
      gld_lds16(BT + (size_t)(n0 + row) * ldb + kcol + cs * 8,
                &lB[(i * 256 + (t & 448)) * 8]);
    }
    __syncthreads();  // drains vmcnt (compiler) -> tile ready
#pragma unroll
    for (int ks = 0; ks < 2; ++ks) {
      bf8 af[4], bfr[4];
      int g = ks * 4 + (l >> 4);
#pragma unroll
      for (int i = 0; i < 4; i++) {
        int r = wm * 64 + i * 16 + (l & 15);
        af[i] = *(const bf8*)&lA[r * 64 + (g ^ (r & 7)) * 8];
      }
#pragma unroll
      for (int j = 0; j < 4; j++) {
        int r = wn * 64 + j * 16 + (l & 15);
        bfr[j] = *(const bf8*)&lB[r * 64 + (g ^ (r & 7)) * 8];
      }
      __builtin_amdgcn_s_setprio(1);
#pragma unroll
      for (int i = 0; i < 4; i++)
#pragma unroll
        for (int j = 0; j < 4; j++) acc[i][j] = MFMA16(af[i], bfr[j], acc[i][j]);
      __builtin_amdgcn_s_setprio(0);
    }
  }

  // epilogue: C/D layout col=lane&15, row=4*(lane>>4)+reg
  if constexpr (EPI == 0 || EPI == 2) {
    __syncthreads();  // all MFMA LDS reads done before reuse
#pragma unroll
    for (int p = 0; p < 2; ++p) {
      if (wm == p) {
#pragma unroll
        for (int jf = 0; jf < 4; ++jf) {
          int lcol = wn * 64 + jf * 16 + (l & 15);
          float bz = bias[n0 + lcol];
#pragma unroll
          for (int ifr = 0; ifr < 4; ++ifr) {
#pragma unroll
            for (int qv = 0; qv < 4; ++qv) {
              int lrow = ifr * 16 + (l >> 4) * 4 + qv;
              float v = acc[ifr][jf][qv] + bz;
              if constexpr (EPI == 2) v = 0.5f * v * (1.0f + erff(v * 0.70710678118f));
              lds[lrow * 132 + lcol] = f2bf(v);
            }
          }
        }
      }
      __syncthreads();
#pragma unroll
      for (int r2 = 0; r2 < 4; ++r2) {
        int c = r2 * 256 + t;
        int lrow = c >> 4, s8 = c & 15;
        int grow = m0 + p * 64 + lrow;
        s4v lo = *(const s4v*)&lds[lrow * 132 + s8 * 8];
        s4v hi = *(const s4v*)&lds[lrow * 132 + s8 * 8 + 4];
        s8v vv = __builtin_shufflevector(lo, hi, 0, 1, 2, 3, 4, 5, 6, 7);
        if (grow < M)
          __builtin_nontemporal_store(vv, (s8v*)(outh + (size_t)grow * N + n0 + s8 * 8));
      }
      __syncthreads();
    }
  } else {
#pragma unroll
    for (int jf = 0; jf < 4; ++jf) {
      int col = n0 + wn * 64 + jf * 16 + (l & 15);
      float bz = (EPI == 3) ? 0.f : bias[col];
#pragma unroll
      for (int ifr = 0; ifr < 4; ++ifr) {
        int rbase = m0 + wm * 64 + ifr * 16 + (l >> 4) * 4;
#pragma unroll
        for (int qv = 0; qv < 4; ++qv) {
          int row = rbase + qv;
          if (row < M) {
            float v = acc[ifr][jf][qv] + bz;
            size_t idx = (size_t)row * N + col;
            if constexpr (EPI == 1) {
              outf[idx] = v + res[idx];
            } else {
              outf[idx] += v;
            }
          }
        }
      }
    }
  }
}

// ---------------- flash attention: swapped QK^T, in-lane P pack, no-max softmax ------
// (R16/R17-proven: absmax 0.03125.)
__global__ __launch_bounds__(256, 4) void attn_kernel(const short* __restrict__ qkv,
                                                      short* __restrict__ aout) {
  __shared__ short lK[64 * 64];
  __shared__ short lV[64 * 64];
  __shared__ short lP[4 * 16 * 64];   // per-wave 16-row P, reused per row-group
  int bid = blockIdx.x;
  int i5 = bid >> 3;
  int bh = ((bid & 7) << 6) + i5 / 5;
  int qt = i5 - (i5 / 5) * 5;          // 0..4, 128 q-rows each
  int b = bh >> 4, h = bh & 15;
  int t = threadIdx.x, w = t >> 6, l = t & 63;
  int m0 = qt * 128;
  const size_t tokbase = (size_t)b * TSEQ;
  unsigned lvb = (unsigned)(uintptr_t)&lV[0];
  const bf8 vones = {0x3F80, 0x3F80, 0x3F80, 0x3F80, 0x3F80, 0x3F80, 0x3F80, 0x3F80};

  bf8 qf[2][2];
#pragma unroll
  for (int g = 0; g < 2; ++g) {
    int tq0 = m0 + w * 32 + g * 16 + (l & 15);
    if (tq0 > TSEQ - 1) tq0 = TSEQ - 1;
    const short* qrow = qkv + (tokbase + tq0) * 3072 + h * 64;
    qf[g][0] = *(const bf8*)(qrow + (l >> 4) * 8);
    qf[g][1] = *(const bf8*)(qrow + 32 + (l >> 4) * 8);
  }

  f32x4 o_acc[2][4] = {};
  f32x4 l_acc[2] = {};

  for (int kt = 0; kt < 10; ++kt) {
    __syncthreads();
#pragma unroll
    for (int i = 0; i < 2; i++) {
      int L = i * 256 + t;
      int key = L >> 3;
      int cd = (L & 7) ^ (key & 7);
      int tok = kt * 64 + key; if (tok > TSEQ - 1) tok = TSEQ - 1;
      gld_lds16(qkv + (tokbase + tok) * 3072 + 1024 + h * 64 + cd * 8,
                &lK[(i * 256 + w * 64) * 8]);
    }
#pragma unroll
    for (int i = 0; i < 2; i++) {
      int L = i * 256 + t;
      int k = (L >> 5) * 4 + ((L >> 1) & 3);
      int c = ((L >> 3) & 3) * 2 + (L & 1);
      int tok = kt * 64 + k; if (tok > TSEQ - 1) tok = TSEQ - 1;
      gld_lds16(qkv + (tokbase + tok) * 3072 + 2048 + h * 64 + c * 8,
                &lV[(i * 256 + w * 64) * 8]);
    }
    __syncthreads();

#pragma unroll
    for (int g = 0; g < 2; ++g) {
      __builtin_amdgcn_s_setprio(1);
#pragma unroll
      for (int nf = 0; nf < 4; ++nf) {
        f32x4 a = {};
#pragma unroll
        for (int ks = 0; ks < 2; ++ks) {
          int keyrow = nf * 16 + (l & 15);
          int cp = (ks * 4 + (l >> 4)) ^ (keyrow & 7);
          bf8 kf = *(const bf8*)&lK[keyrow * 64 + cp * 8];
          a = MFMA16(kf, qf[g][ks], a);
        }
        float s0 = a[0] * 0.18033688011f, s1 = a[1] * 0.18033688011f;
        float s2 = a[2] * 0.18033688011f, s3 = a[3] * 0.18033688011f;
        if (kt == 9) {
          int kb = 576 + nf * 16 + 4 * (l >> 4);
          if (kb + 0 >= TSEQ) s0 = -1e30f;
          if (kb + 1 >= TSEQ) s1 = -1e30f;
          if (kb + 2 >= TSEQ) s2 = -1e30f;
          if (kb + 3 >= TSEQ) s3 = -1e30f;
        }
        float e0, e1, e2, e3;
        asm("v_exp_f32 %0, %1" : "=v"(e0) : "v"(s0));
        asm("v_exp_f32 %0, %1" : "=v"(e1) : "v"(s1));
        asm("v_exp_f32 %0, %1" : "=v"(e2) : "v"(s2));
        asm("v_exp_f32 %0, %1" : "=v"(e3) : "v"(s3));
        unsigned d0, d1;
        asm("v_cvt_pk_bf16_f32 %0, %1, %2" : "=v"(d0) : "v"(e0), "v"(e1));
        asm("v_cvt_pk_bf16_f32 %0, %1, %2" : "=v"(d1) : "v"(e2), "v"(e3));
        int row = l & 15;
        int chunk = 2 * nf + ((l >> 4) >> 1);
        int cs = chunk ^ (row & 7);
        int base = w * 1024 + row * 64 + cs * 8 + 4 * ((l >> 4) & 1);
        *(unsigned*)&lP[base] = d0;
        *(unsigned*)&lP[base + 2] = d1;
      }
      __builtin_amdgcn_s_setprio(0);
      asm volatile("s_waitcnt lgkmcnt(0)" ::: "memory");
      __builtin_amdgcn_sched_barrier(0);

#pragma unroll
      for (int ks = 0; ks < 2; ++ks) {
        int qr = l & 15;
        int cp = (ks * 4 + (l >> 4)) ^ (qr & 7);
        bf8 pf = *(const bf8*)&lP[w * 1024 + qr * 64 + cp * 8];
        unsigned kq0 = (unsigned)(ks * 8 + (l >> 4) * 2);
        unsigned abase = lvb + kq0 * 512u + (unsigned)(l & 15) * 8u;
        s4v ra0, ra1, rb0, rb1, rc0, rc1, rd0, rd1;
        asm volatile("ds_read_b64_tr_b16 %0, %1" : "=v"(ra0) : "v"(abase));
        asm volatile("ds_read_b64_tr_b16 %0, %1" : "=v"(ra1) : "v"(abase + 512u));
        asm volatile("ds_read_b64_tr_b16 %0, %1" : "=v"(rb0) : "v"(abase + 128u));
        asm volatile("ds_read_b64_tr_b16 %0, %1" : "=v"(rb1) : "v"(abase + 640u));
        asm volatile("ds_read_b64_tr_b16 %0, %1" : "=v"(rc0) : "v"(abase + 256u));
        asm volatile("ds_read_b64_tr_b16 %0, %1" : "=v"(rc1) : "v"(abase + 768u));
        asm volatile("ds_read_b64_tr_b16 %0, %1" : "=v"(rd0) : "v"(abase + 384u));
        asm volatile("ds_read_b64_tr_b16 %0, %1" : "=v"(rd1) : "v"(abase + 896u));
        asm volatile("s_waitcnt lgkmcnt(0)" ::: "memory");
        __builtin_amdgcn_sched_barrier(0);
        bf8 vfa = __builtin_shufflevector(ra0, ra1, 0, 1, 2, 3, 4, 5, 6, 7);
        bf8 vfb = __builtin_shufflevector(rb0, rb1, 0, 1, 2, 3, 4, 5, 6, 7);
        bf8 vfc = __builtin_shufflevector(rc0, rc1, 0, 1, 2, 3, 4, 5, 6, 7);
        bf8 vfd = __builtin_shufflevector(rd0, rd1, 0, 1, 2, 3, 4, 5, 6, 7);
        __builtin_amdgcn_s_setprio(1);
        l_acc[g] = MFMA16(pf, vones, l_acc[g]);
        o_acc[g][0] = MFMA16(pf, vfa, o_acc[g][0]);
        o_acc[g][1] = MFMA16(pf, vfb, o_acc[g][1]);
        o_acc[g][2] = MFMA16(pf, vfc, o_acc[g][2]);
        o_acc[g][3] = MFMA16(pf, vfd, o_acc[g][3]);
        __builtin_amdgcn_s_setprio(0);
      }
    }
  }
#pragma unroll
  for (int g = 0; g < 2; ++g)
#pragma unroll
    for (int df = 0; df < 4; df++)
#pragma unroll
      for (int q = 0; q < 4; q++) {
        int tq = m0 + w * 32 + g * 16 + (l >> 4) * 4 + q;
        if (tq < TSEQ) {
          float val = o_acc[g][df][q] / l_acc[g][q];
          aout[(tokbase + tq) * DIMM + h * 64 + df * 16 + (l & 15)] = f2bf(val);
        }
      }
}

// ---------------- launch ----------------
extern "C" void kernel_launch(void* const* d_in, const int* in_sizes, int n_in,
                              void* d_out, int out_size, void* d_ws, size_t ws_size,
                              hipStream_t stream) {
  const float* x      = (const float*)d_in[0];
  const float* ln1_g  = (const float*)d_in[1];
  const float* ln1_b  = (const float*)d_in[2];
  const float* qkv_w  = (const float*)d_in[3];
  const float* qkv_b  = (const float*)d_in[4];
  const float* proj_w = (const float*)d_in[5];
  const float* proj_b = (const float*)d_in[6];
  const float* ln2_g  = (const float*)d_in[7];
  const float* ln2_b  = (const float*)d_in[8];
  const float* fc1_w  = (const float*)d_in[9];
  const float* fc1_b  = (const float*)d_in[10];
  const float* fc2_w  = (const float*)d_in[11];
  const float* fc2_b  = (const float*)d_in[12];
  float* out = (float*)d_out;

  const size_t REQ = (size_t)(12582912 + (size_t)M_TOK * 1024 + (size_t)M_TOK * 3072) * 2;
  if (ws_size < REQ) return;

  short* w_qkv  = (short*)d_ws;                      // [3072][1024]
  short* w_proj = w_qkv + (size_t)3072 * 1024;       // [1024][1024]
  short* w_fc1  = w_proj + (size_t)1024 * 1024;      // [4096][1024]
  short* w_fc2  = w_fc1 + (size_t)4096 * 1024;       // [1024][4096]
  short* bufA   = w_fc2 + (size_t)1024 * 4096;       // [M][1024]
  short* bufB   = bufA + (size_t)M_TOK * 1024;       // [M][3072] / FFN h-chunks [M][2048]

  dim3 blk(256);
  conv_t_kernel<<<dim3(3072 / 32, 1024 / 32), blk, 0, stream>>>(qkv_w, w_qkv, 1024, 3072);
  conv_t_kernel<<<dim3(1024 / 32, 1024 / 32), blk, 0, stream>>>(proj_w, w_proj, 1024, 1024);
  conv_t_kernel<<<dim3(4096 / 32, 1024 / 32), blk, 0, stream>>>(fc1_w, w_fc1, 1024, 4096);
  conv_t_kernel<<<dim3(1024 / 32, 4096 / 32), blk, 0, stream>>>(fc2_w, w_fc2, 4096, 1024);
  // LN1: x -> bufA   (wave-per-row, 4616*4 = 18464)
  ln_kernel<<<M_TOK / 4, blk, 0, stream>>>(x, ln1_g, ln1_b, bufA);
  // QKV: bufA @ w_qkv^T -> bufB   (grid 3480)
  gemm_kernel<0><<<NTMK * 24, blk, 0, stream>>>(bufA, w_qkv, qkv_b, nullptr, bufB, nullptr,
                                                M_TOK, 1024, 3072, 1024, 1024, NTMK, 24);
  // attention: bufB -> bufA   (flat 2560, XCD-clustered 5 q-tiles per (b,h))
  attn_kernel<<<2560, blk, 0, stream>>>(bufB, bufA);
  // proj + residual(x) -> out (x1)   (grid 1160)
  gemm_kernel<1><<<NTMK * 8, blk, 0, stream>>>(bufA, w_proj, proj_b, x, nullptr, out,
                                               M_TOK, 1024, 1024, 1024, 1024, NTMK, 8);
  // LN2 on x1 -> bufA
  ln_kernel<<<M_TOK / 4, blk, 0, stream>>>(out, ln2_g, ln2_b, bufA);
  // FFN in 2 hidden-dim chunks of 2048 (h chunk lives in bufB)
  for (int c = 0; c < 2; ++c) {
    // FC1 chunk + GELU: bufA @ w_fc1[c*2048:+2048]^T -> bufB [M][2048]  (grid 2320)
    gemm_kernel<2><<<NTMK * 16, blk, 0, stream>>>(bufA, w_fc1 + (size_t)c * 2048 * 1024,
                                                  fc1_b + c * 2048, nullptr, bufB, nullptr,
                                                  M_TOK, 1024, 2048, 1024, 1024, NTMK, 16);
    // FC2 chunk: out (+)= bufB @ w_fc2[:, c*2048:+2048]^T  (grid 1160)
    if (c == 0) {
      gemm_kernel<1><<<NTMK * 8, blk, 0, stream>>>(bufB, w_fc2 + (size_t)c * 2048, fc2_b,
                                                   out, nullptr, out, M_TOK, 2048, 1024,
                                                   2048, 4096, NTMK, 8);
    } else {
      gemm_kernel<3><<<NTMK * 8, blk, 0, stream>>>(bufB, w_fc2 + (size_t)c * 2048, fc2_b,
                                                   out, nullptr, out, M_TOK, 2048, 1024,
                                                   2048, 4096, NTMK, 8);
    }
  }
}

// Round 20
// 865.580 us; speedup vs baseline: 1.3250x; 1.0704x over previous
//
#include <hip/hip_runtime.h>

// ---------------- constants ----------------
#define M_TOK 18464      // 32*577 tokens
#define TSEQ  577
#define NBATCH 32
#define NH    16
#define HD    64
#define DIMM  1024
#define HIDD  4096
#define NTMK  145        // ceil(18464/128)

typedef __attribute__((ext_vector_type(4))) float f32x4;
typedef __attribute__((ext_vector_type(8))) short bf8;   // 8 bf16 (MFMA A/B frag)
typedef __attribute__((ext_vector_type(8))) short s8v;
typedef __attribute__((ext_vector_type(4))) short s4v;

__device__ __forceinline__ short f2bf(float f) {
  union { float f; unsigned u; } c; c.f = f;
  unsigned u = c.u;
  unsigned r = (u + 0x7fffu + ((u >> 16) & 1u)) >> 16;  // RNE
  return (short)r;
}

// async global->LDS, 16B per lane; dest = wave-uniform base + lane*16
__device__ __forceinline__ void gld_lds16(const short* g, short* l) {
  __builtin_amdgcn_global_load_lds(
      (const __attribute__((address_space(1))) unsigned int*)g,
      (__attribute__((address_space(3))) unsigned int*)l, 16, 0, 0);
}

#define MFMA16(a, b, c) __builtin_amdgcn_mfma_f32_16x16x32_bf16(a, b, c, 0, 0, 0)

// ---------------- weight convert + transpose: W[K][N] f32 -> WT[N][K] bf16 ----------------
__global__ __launch_bounds__(256) void conv_t_kernel(const float* __restrict__ W,
                                                     short* __restrict__ WT,
                                                     int K, int N) {
  __shared__ short tile[32][33];
  int bx = blockIdx.x;  // n tile
  int by = blockIdx.y;  // k tile
  int t = threadIdx.x;
  int c = t & 31, r = t >> 5;  // 32 cols x 8 rows
#pragma unroll
  for (int rr = r; rr < 32; rr += 8)
    tile[rr][c] = f2bf(W[(size_t)(by * 32 + rr) * N + bx * 32 + c]);
  __syncthreads();
#pragma unroll
  for (int rr = r; rr < 32; rr += 8)
    WT[(size_t)(bx * 32 + rr) * K + by * 32 + c] = tile[c][rr];
}

// ---------------- layernorm: wave-per-row, f32 [M][1024] -> bf16 [M][1024] ----------------
__global__ __launch_bounds__(256) void ln_kernel(const float* __restrict__ x,
                                                 const float* __restrict__ g,
                                                 const float* __restrict__ b,
                                                 short* __restrict__ out) {
  int w = threadIdx.x >> 6, l = threadIdx.x & 63;
  int row = blockIdx.x * 4 + w;   // grid 4616 * 4 = 18464 exactly
  const float4* xr = (const float4*)(x + (size_t)row * DIMM);
  const float4* g4 = (const float4*)g;
  const float4* b4 = (const float4*)b;
  float4 v[4];
  float s1 = 0.f;
#pragma unroll
  for (int i = 0; i < 4; ++i) {
    v[i] = xr[i * 64 + l];
    s1 += v[i].x + v[i].y + v[i].z + v[i].w;
  }
#pragma unroll
  for (int m = 1; m < 64; m <<= 1) s1 += __shfl_xor(s1, m);
  float mu = s1 * (1.0f / 1024.0f);
  float s2 = 0.f;
#pragma unroll
  for (int i = 0; i < 4; ++i) {
    float dx = v[i].x - mu, dy = v[i].y - mu, dz = v[i].z - mu, dw = v[i].w - mu;
    s2 += dx * dx + dy * dy + dz * dz + dw * dw;
  }
#pragma unroll
  for (int m = 1; m < 64; m <<= 1) s2 += __shfl_xor(s2, m);
  float rs = rsqrtf(s2 * (1.0f / 1024.0f) + 1e-6f);
#pragma unroll
  for (int i = 0; i < 4; ++i) {
    float4 gv = g4[i * 64 + l], bv = b4[i * 64 + l];
    s4v o;
    o[0] = f2bf((v[i].x - mu) * rs * gv.x + bv.x);
    o[1] = f2bf((v[i].y - mu) * rs * gv.y + bv.y);
    o[2] = f2bf((v[i].z - mu) * rs * gv.z + bv.z);
    o[3] = f2bf((v[i].w - mu) * rs * gv.w + bv.w);
    *(s4v*)(out + (size_t)row * DIMM + (i * 64 + l) * 4) = o;
  }
}

// ---------------- GEMM 128x128x64, single-buffer, 4 blocks/CU, 4x2 XCD region map ------
// C[M][N] = A[M][K](bf16, lda) @ BT[N][K](bf16, ldb)^T + bias
// EPI 0: bf16 = C+bias | EPI 1: f32 = C+bias+res | EPI 2: bf16 = gelu(C+bias) | EPI 3: f32 += C
// R13/R17-proven best structure (reproduced R19: 921/926 us).
// R18 lesson: deep-pipelined 256^2 lands at MfmaUtil 15%; this TLP-first form wins at 21%.
// R14 lesson: bounds (256,5) spills the accumulator. Keep 4.
template <int EPI>
__global__ __launch_bounds__(256, 4) void gemm_kernel(const short* __restrict__ A,
                                                      const short* __restrict__ BT,
                                                      const float* __restrict__ bias,
                                                      const float* res, short* outh,
                                                      float* outf, int M, int K, int N,
                                                      int lda, int ldb, int ntm, int ntn) {
  __shared__ short lds[16384];   // 32 KB: lA | lB during K-loop, C-staging in epilogue
  short* lA = lds;
  short* lB = lds + 8192;
  // bijective gid: contiguous slice of region-major tile list per XCD
  int grid = ntm * ntn;
  int qd = grid >> 3, rd = grid & 7;
  int x = blockIdx.x & 7, il = blockIdx.x >> 3;
  int gid = x * qd + (x < rd ? x : rd) + il;
  // regions: 4 tm-groups x 2 tn-halves, region-major (i*2+j), tn-inner within region
  int tnh = ntn >> 1;
  int qa = ntm >> 2, ra = ntm & 3;
  int tm = 0, tn = 0, rem = gid;
#pragma unroll
  for (int rg = 0; rg < 8; ++rg) {
    int i = rg >> 1, j = rg & 1;
    int rows = qa + (i < ra ? 1 : 0);
    int cnt = rows * tnh;
    if (rem < cnt) {
      int rowstart = i * qa + (i < ra ? i : ra);
      tm = rowstart + rem / tnh;
      tn = j * tnh + rem % tnh;
      rem = 0x7fffffff;  // found; skip remaining regions
    } else if (rem != 0x7fffffff) {
      rem -= cnt;
    }
  }
  int m0 = tm * 128, n0 = tn * 128;
  int t = threadIdx.x, l = t & 63;
  int w = t >> 6, wm = w >> 1, wn = w & 1;
  f32x4 acc[4][4] = {};
  const int NKT = K >> 6;

  for (int it = 0; it < NKT; ++it) {
    __syncthreads();  // previous tile's readers done
    int kcol = it << 6;
#pragma unroll
    for (int i = 0; i < 4; i++) {
      int L = i * 256 + t;
      int row = L >> 3, cs = (L & 7) ^ (row & 7);
      int mg = m0 + row;
      if (mg > M - 1) mg = M - 1;
      gld_lds16(A + (size_t)mg * lda + kcol + cs * 8,
                &lA[(i * 256 + (t & 448)) * 8]);
    }
#pragma unroll
    for (int i = 0; i < 4; i++) {
      int L = i * 256 + t;
      int row = L >> 3, cs = (L & 7) ^ (row & 7);
      gld_lds16(BT + (size_t)(n0 + row) * ldb + kcol + cs * 8,
                &lB[(i * 256 + (t & 448)) * 8]);
    }
    __syncthreads();  // drains vmcnt (compiler) -> tile ready
#pragma unroll
    for (int ks = 0; ks < 2; ++ks) {
      bf8 af[4], bfr[4];
      int g = ks * 4 + (l >> 4);
#pragma unroll
      for (int i = 0; i < 4; i++) {
        int r = wm * 64 + i * 16 + (l & 15);
        af[i] = *(const bf8*)&lA[r * 64 + (g ^ (r & 7)) * 8];
      }
#pragma unroll
      for (int j = 0; j < 4; j++) {
        int r = wn * 64 + j * 16 + (l & 15);
        bfr[j] = *(const bf8*)&lB[r * 64 + (g ^ (r & 7)) * 8];
      }
      __builtin_amdgcn_s_setprio(1);
#pragma unroll
      for (int i = 0; i < 4; i++)
#pragma unroll
        for (int j = 0; j < 4; j++) acc[i][j] = MFMA16(af[i], bfr[j], acc[i][j]);
      __builtin_amdgcn_s_setprio(0);
    }
  }

  // epilogue: C/D layout col=lane&15, row=4*(lane>>4)+reg
  if constexpr (EPI == 0 || EPI == 2) {
    __syncthreads();  // all MFMA LDS reads done before reuse
#pragma unroll
    for (int p = 0; p < 2; ++p) {
      if (wm == p) {
#pragma unroll
        for (int jf = 0; jf < 4; ++jf) {
          int lcol = wn * 64 + jf * 16 + (l & 15);
          float bz = bias[n0 + lcol];
#pragma unroll
          for (int ifr = 0; ifr < 4; ++ifr) {
#pragma unroll
            for (int qv = 0; qv < 4; ++qv) {
              int lrow = ifr * 16 + (l >> 4) * 4 + qv;
              float v = acc[ifr][jf][qv] + bz;
              if constexpr (EPI == 2) v = 0.5f * v * (1.0f + erff(v * 0.70710678118f));
              lds[lrow * 132 + lcol] = f2bf(v);
            }
          }
        }
      }
      __syncthreads();
#pragma unroll
      for (int r2 = 0; r2 < 4; ++r2) {
        int c = r2 * 256 + t;
        int lrow = c >> 4, s8 = c & 15;
        int grow = m0 + p * 64 + lrow;
        s4v lo = *(const s4v*)&lds[lrow * 132 + s8 * 8];
        s4v hi = *(const s4v*)&lds[lrow * 132 + s8 * 8 + 4];
        s8v vv = __builtin_shufflevector(lo, hi, 0, 1, 2, 3, 4, 5, 6, 7);
        if (grow < M)
          __builtin_nontemporal_store(vv, (s8v*)(outh + (size_t)grow * N + n0 + s8 * 8));
      }
      __syncthreads();
    }
  } else {
#pragma unroll
    for (int jf = 0; jf < 4; ++jf) {
      int col = n0 + wn * 64 + jf * 16 + (l & 15);
      float bz = (EPI == 3) ? 0.f : bias[col];
#pragma unroll
      for (int ifr = 0; ifr < 4; ++ifr) {
        int rbase = m0 + wm * 64 + ifr * 16 + (l >> 4) * 4;
#pragma unroll
        for (int qv = 0; qv < 4; ++qv) {
          int row = rbase + qv;
          if (row < M) {
            float v = acc[ifr][jf][qv] + bz;
            size_t idx = (size_t)row * N + col;
            if constexpr (EPI == 1) {
              outf[idx] = v + res[idx];
            } else {
              outf[idx] += v;
            }
          }
        }
      }
    }
  }
}

// ---------------- flash attention: swapped QK^T, in-lane P pack, no-max softmax ------
// (R16/R17/R19-proven: absmax 0.03125.)
__global__ __launch_bounds__(256, 4) void attn_kernel(const short* __restrict__ qkv,
                                                      short* __restrict__ aout) {
  __shared__ short lK[64 * 64];
  __shared__ short lV[64 * 64];
  __shared__ short lP[4 * 16 * 64];   // per-wave 16-row P, reused per row-group
  int bid = blockIdx.x;
  int i5 = bid >> 3;
  int bh = ((bid & 7) << 6) + i5 / 5;
  int qt = i5 - (i5 / 5) * 5;          // 0..4, 128 q-rows each
  int b = bh >> 4, h = bh & 15;
  int t = threadIdx.x, w = t >> 6, l = t & 63;
  int m0 = qt * 128;
  const size_t tokbase = (size_t)b * TSEQ;
  unsigned lvb = (unsigned)(uintptr_t)&lV[0];
  const bf8 vones = {0x3F80, 0x3F80, 0x3F80, 0x3F80, 0x3F80, 0x3F80, 0x3F80, 0x3F80};

  bf8 qf[2][2];
#pragma unroll
  for (int g = 0; g < 2; ++g) {
    int tq0 = m0 + w * 32 + g * 16 + (l & 15);
    if (tq0 > TSEQ - 1) tq0 = TSEQ - 1;
    const short* qrow = qkv + (tokbase + tq0) * 3072 + h * 64;
    qf[g][0] = *(const bf8*)(qrow + (l >> 4) * 8);
    qf[g][1] = *(const bf8*)(qrow + 32 + (l >> 4) * 8);
  }

  f32x4 o_acc[2][4] = {};
  f32x4 l_acc[2] = {};

  for (int kt = 0; kt < 10; ++kt) {
    __syncthreads();
#pragma unroll
    for (int i = 0; i < 2; i++) {
      int L = i * 256 + t;
      int key = L >> 3;
      int cd = (L & 7) ^ (key & 7);
      int tok = kt * 64 + key; if (tok > TSEQ - 1) tok = TSEQ - 1;
      gld_lds16(qkv + (tokbase + tok) * 3072 + 1024 + h * 64 + cd * 8,
                &lK[(i * 256 + w * 64) * 8]);
    }
#pragma unroll
    for (int i = 0; i < 2; i++) {
      int L = i * 256 + t;
      int k = (L >> 5) * 4 + ((L >> 1) & 3);
      int c = ((L >> 3) & 3) * 2 + (L & 1);
      int tok = kt * 64 + k; if (tok > TSEQ - 1) tok = TSEQ - 1;
      gld_lds16(qkv + (tokbase + tok) * 3072 + 2048 + h * 64 + c * 8,
                &lV[(i * 256 + w * 64) * 8]);
    }
    __syncthreads();

#pragma unroll
    for (int g = 0; g < 2; ++g) {
      __builtin_amdgcn_s_setprio(1);
#pragma unroll
      for (int nf = 0; nf < 4; ++nf) {
        f32x4 a = {};
#pragma unroll
        for (int ks = 0; ks < 2; ++ks) {
          int keyrow = nf * 16 + (l & 15);
          int cp = (ks * 4 + (l >> 4)) ^ (keyrow & 7);
          bf8 kf = *(const bf8*)&lK[keyrow * 64 + cp * 8];
          a = MFMA16(kf, qf[g][ks], a);
        }
        float s0 = a[0] * 0.18033688011f, s1 = a[1] * 0.18033688011f;
        float s2 = a[2] * 0.18033688011f, s3 = a[3] * 0.18033688011f;
        if (kt == 9) {
          int kb = 576 + nf * 16 + 4 * (l >> 4);
          if (kb + 0 >= TSEQ) s0 = -1e30f;
          if (kb + 1 >= TSEQ) s1 = -1e30f;
          if (kb + 2 >= TSEQ) s2 = -1e30f;
          if (kb + 3 >= TSEQ) s3 = -1e30f;
        }
        float e0, e1, e2, e3;
        asm("v_exp_f32 %0, %1" : "=v"(e0) : "v"(s0));
        asm("v_exp_f32 %0, %1" : "=v"(e1) : "v"(s1));
        asm("v_exp_f32 %0, %1" : "=v"(e2) : "v"(s2));
        asm("v_exp_f32 %0, %1" : "=v"(e3) : "v"(s3));
        unsigned d0, d1;
        asm("v_cvt_pk_bf16_f32 %0, %1, %2" : "=v"(d0) : "v"(e0), "v"(e1));
        asm("v_cvt_pk_bf16_f32 %0, %1, %2" : "=v"(d1) : "v"(e2), "v"(e3));
        int row = l & 15;
        int chunk = 2 * nf + ((l >> 4) >> 1);
        int cs = chunk ^ (row & 7);
        int base = w * 1024 + row * 64 + cs * 8 + 4 * ((l >> 4) & 1);
        *(unsigned*)&lP[base] = d0;
        *(unsigned*)&lP[base + 2] = d1;
      }
      __builtin_amdgcn_s_setprio(0);
      asm volatile("s_waitcnt lgkmcnt(0)" ::: "memory");
      __builtin_amdgcn_sched_barrier(0);

#pragma unroll
      for (int ks = 0; ks < 2; ++ks) {
        int qr = l & 15;
        int cp = (ks * 4 + (l >> 4)) ^ (qr & 7);
        bf8 pf = *(const bf8*)&lP[w * 1024 + qr * 64 + cp * 8];
        unsigned kq0 = (unsigned)(ks * 8 + (l >> 4) * 2);
        unsigned abase = lvb + kq0 * 512u + (unsigned)(l & 15) * 8u;
        s4v ra0, ra1, rb0, rb1, rc0, rc1, rd0, rd1;
        asm volatile("ds_read_b64_tr_b16 %0, %1" : "=v"(ra0) : "v"(abase));
        asm volatile("ds_read_b64_tr_b16 %0, %1" : "=v"(ra1) : "v"(abase + 512u));
        asm volatile("ds_read_b64_tr_b16 %0, %1" : "=v"(rb0) : "v"(abase + 128u));
        asm volatile("ds_read_b64_tr_b16 %0, %1" : "=v"(rb1) : "v"(abase + 640u));
        asm volatile("ds_read_b64_tr_b16 %0, %1" : "=v"(rc0) : "v"(abase + 256u));
        asm volatile("ds_read_b64_tr_b16 %0, %1" : "=v"(rc1) : "v"(abase + 768u));
        asm volatile("ds_read_b64_tr_b16 %0, %1" : "=v"(rd0) : "v"(abase + 384u));
        asm volatile("ds_read_b64_tr_b16 %0, %1" : "=v"(rd1) : "v"(abase + 896u));
        asm volatile("s_waitcnt lgkmcnt(0)" ::: "memory");
        __builtin_amdgcn_sched_barrier(0);
        bf8 vfa = __builtin_shufflevector(ra0, ra1, 0, 1, 2, 3, 4, 5, 6, 7);
        bf8 vfb = __builtin_shufflevector(rb0, rb1, 0, 1, 2, 3, 4, 5, 6, 7);
        bf8 vfc = __builtin_shufflevector(rc0, rc1, 0, 1, 2, 3, 4, 5, 6, 7);
        bf8 vfd = __builtin_shufflevector(rd0, rd1, 0, 1, 2, 3, 4, 5, 6, 7);
        __builtin_amdgcn_s_setprio(1);
        l_acc[g] = MFMA16(pf, vones, l_acc[g]);
        o_acc[g][0] = MFMA16(pf, vfa, o_acc[g][0]);
        o_acc[g][1] = MFMA16(pf, vfb, o_acc[g][1]);
        o_acc[g][2] = MFMA16(pf, vfc, o_acc[g][2]);
        o_acc[g][3] = MFMA16(pf, vfd, o_acc[g][3]);
        __builtin_amdgcn_s_setprio(0);
      }
    }
  }
#pragma unroll
  for (int g = 0; g < 2; ++g)
#pragma unroll
    for (int df = 0; df < 4; df++)
#pragma unroll
      for (int q = 0; q < 4; q++) {
        int tq = m0 + w * 32 + g * 16 + (l >> 4) * 4 + q;
        if (tq < TSEQ) {
          float val = o_acc[g][df][q] / l_acc[g][q];
          aout[(tokbase + tq) * DIMM + h * 64 + df * 16 + (l & 15)] = f2bf(val);
        }
      }
}

// ---------------- launch ----------------
extern "C" void kernel_launch(void* const* d_in, const int* in_sizes, int n_in,
                              void* d_out, int out_size, void* d_ws, size_t ws_size,
                              hipStream_t stream) {
  const float* x      = (const float*)d_in[0];
  const float* ln1_g  = (const float*)d_in[1];
  const float* ln1_b  = (const float*)d_in[2];
  const float* qkv_w  = (const float*)d_in[3];
  const float* qkv_b  = (const float*)d_in[4];
  const float* proj_w = (const float*)d_in[5];
  const float* proj_b = (const float*)d_in[6];
  const float* ln2_g  = (const float*)d_in[7];
  const float* ln2_b  = (const float*)d_in[8];
  const float* fc1_w  = (const float*)d_in[9];
  const float* fc1_b  = (const float*)d_in[10];
  const float* fc2_w  = (const float*)d_in[11];
  const float* fc2_b  = (const float*)d_in[12];
  float* out = (float*)d_out;

  const size_t REQ  = (size_t)(12582912 + (size_t)M_TOK * 1024 + (size_t)M_TOK * 3072) * 2;
  const size_t REQ2 = (size_t)(12582912 + (size_t)M_TOK * 1024 + (size_t)M_TOK * 4096) * 2;
  if (ws_size < REQ) return;
  const bool fused_ffn = (ws_size >= REQ2);  // bufB can hold [M][4096] bf16

  short* w_qkv  = (short*)d_ws;                      // [3072][1024]
  short* w_proj = w_qkv + (size_t)3072 * 1024;       // [1024][1024]
  short* w_fc1  = w_proj + (size_t)1024 * 1024;      // [4096][1024]
  short* w_fc2  = w_fc1 + (size_t)4096 * 1024;       // [1024][4096]
  short* bufA   = w_fc2 + (size_t)1024 * 4096;       // [M][1024]
  short* bufB   = bufA + (size_t)M_TOK * 1024;       // [M][3072] / FFN h-buf

  dim3 blk(256);
  conv_t_kernel<<<dim3(3072 / 32, 1024 / 32), blk, 0, stream>>>(qkv_w, w_qkv, 1024, 3072);
  conv_t_kernel<<<dim3(1024 / 32, 1024 / 32), blk, 0, stream>>>(proj_w, w_proj, 1024, 1024);
  conv_t_kernel<<<dim3(4096 / 32, 1024 / 32), blk, 0, stream>>>(fc1_w, w_fc1, 1024, 4096);
  conv_t_kernel<<<dim3(1024 / 32, 4096 / 32), blk, 0, stream>>>(fc2_w, w_fc2, 4096, 1024);
  // LN1: x -> bufA   (wave-per-row, 4616*4 = 18464)
  ln_kernel<<<M_TOK / 4, blk, 0, stream>>>(x, ln1_g, ln1_b, bufA);
  // QKV: bufA @ w_qkv^T -> bufB   (grid 3480)
  gemm_kernel<0><<<NTMK * 24, blk, 0, stream>>>(bufA, w_qkv, qkv_b, nullptr, bufB, nullptr,
                                                M_TOK, 1024, 3072, 1024, 1024, NTMK, 24);
  // attention: bufB -> bufA   (flat 2560, XCD-clustered 5 q-tiles per (b,h))
  attn_kernel<<<2560, blk, 0, stream>>>(bufB, bufA);
  // proj + residual(x) -> out (x1)   (grid 1160)
  gemm_kernel<1><<<NTMK * 8, blk, 0, stream>>>(bufA, w_proj, proj_b, x, nullptr, out,
                                               M_TOK, 1024, 1024, 1024, 1024, NTMK, 8);
  // LN2 on x1 -> bufA
  ln_kernel<<<M_TOK / 4, blk, 0, stream>>>(out, ln2_g, ln2_b, bufA);

  if (fused_ffn) {
    // FC1 + GELU single pass: bufA @ w_fc1^T -> bufB [M][4096]   (grid 4640, eff 90.6%)
    gemm_kernel<2><<<NTMK * 32, blk, 0, stream>>>(bufA, w_fc1, fc1_b, nullptr, bufB, nullptr,
                                                  M_TOK, 1024, 4096, 1024, 1024, NTMK, 32);
    // FC2 single pass: out = bufB @ w_fc2^T + bias + out   (grid 1160, K=4096)
    gemm_kernel<1><<<NTMK * 8, blk, 0, stream>>>(bufB, w_fc2, fc2_b, out, nullptr, out,
                                                 M_TOK, 4096, 1024, 4096, 4096, NTMK, 8);
  } else {
    // fallback: FFN in 2 hidden-dim chunks of 2048 (R17/R19-proven)
    for (int c = 0; c < 2; ++c) {
      gemm_kernel<2><<<NTMK * 16, blk, 0, stream>>>(bufA, w_fc1 + (size_t)c * 2048 * 1024,
                                                    fc1_b + c * 2048, nullptr, bufB, nullptr,
                                                    M_TOK, 1024, 2048, 1024, 1024, NTMK, 16);
      if (c == 0) {
        gemm_kernel<1><<<NTMK * 8, blk, 0, stream>>>(bufB, w_fc2 + (size_t)c * 2048, fc2_b,
                                                     out, nullptr, out, M_TOK, 2048, 1024,
                                                     2048, 4096, NTMK, 8);
      } else {
        gemm_kernel<3><<<NTMK * 8, blk, 0, stream>>>(bufB, w_fc2 + (size_t)c * 2048, fc2_b,
                                                     out, nullptr, out, M_TOK, 2048, 1024,
                                                     2048, 4096, NTMK, 8);
      }
    }
  }
}